// Round 14
// baseline (1457.000 us; speedup 1.0000x reference)
//
#include <hip/hip_runtime.h>
#include <math.h>

typedef unsigned short u16;
typedef short s16x8 __attribute__((ext_vector_type(8)));
typedef float f32x4 __attribute__((ext_vector_type(4)));

#define GLOAD16(gp, lp)                                                        \
  __builtin_amdgcn_global_load_lds(                                            \
      (const __attribute__((address_space(1))) void*)(gp),                     \
      (__attribute__((address_space(3))) void*)(lp), 16, 0, 0)

__device__ __forceinline__ u16 f2bf(float f) {
  union { float f; unsigned u; } v; v.f = f;
  unsigned r = v.u + 0x7fffu + ((v.u >> 16) & 1u);  // RNE
  return (u16)(r >> 16);
}

// ------- kernel A: transpose+cvt (y=0..5) + x cvt (y=6). (R12 verbatim)
__global__ __launch_bounds__(256) void prep_kernel(
    const float* __restrict__ in0, const float* __restrict__ in1,
    const float* __restrict__ in2, const float* __restrict__ in3,
    const float* __restrict__ in4, const float* __restrict__ in5,
    const float* __restrict__ xin,
    u16* __restrict__ o01, u16* __restrict__ o23,
    u16* __restrict__ o4, u16* __restrict__ o5, u16* __restrict__ xout) {
  const int mat = blockIdx.y;
  const int t = threadIdx.x;
  if (mat == 6) {
    if (blockIdx.x >= 8192) return;
    size_t i = ((size_t)blockIdx.x * 256 + t) * 8;
    float4 a = *(const float4*)(xin + i);
    float4 b = *(const float4*)(xin + i + 4);
    s16x8 v;
    v[0] = (short)f2bf(a.x); v[1] = (short)f2bf(a.y);
    v[2] = (short)f2bf(a.z); v[3] = (short)f2bf(a.w);
    v[4] = (short)f2bf(b.x); v[5] = (short)f2bf(b.y);
    v[6] = (short)f2bf(b.z); v[7] = (short)f2bf(b.w);
    *(s16x8*)(xout + i) = v;
    return;
  }
  __shared__ float s[64 * 65];
  const float* in; u16* out;
  switch (mat) {
    case 0: in = in0; out = o01; break;
    case 1: in = in1; out = o01; break;
    case 2: in = in2; out = o23; break;
    case 3: in = in3; out = o23; break;
    case 4: in = in4; out = o4; break;
    default: in = in5; out = o5; break;
  }
  const int R = (mat < 4) ? 4096 : 11008;
  const int C = (mat < 4) ? 11008 : 4096;
  const int nTc = C >> 6;
  const int tr = blockIdx.x / nTc, tc = blockIdx.x - tr * nTc;
  const int r0 = tr << 6, c0 = tc << 6;
#pragma unroll
  for (int p = 0; p < 4; ++p) {
    const int lr = p * 16 + (t >> 4);
    const int lc = (t & 15) * 4;
    float4 v = *(const float4*)(in + (size_t)(r0 + lr) * C + (c0 + lc));
    float* sp = &s[lr * 65 + lc];
    sp[0] = v.x; sp[1] = v.y; sp[2] = v.z; sp[3] = v.w;
  }
  __syncthreads();
#pragma unroll
  for (int q = 0; q < 2; ++q) {
    const int oc = q * 32 + (t >> 3);
    const int orr = (t & 7) * 8;
    s16x8 v;
#pragma unroll
    for (int i = 0; i < 8; ++i) v[i] = (short)f2bf(s[(orr + i) * 65 + oc]);
    const int f = c0 + oc;
    size_t orow;
    if (mat < 4) orow = (size_t)((f >> 4) << 5) + ((mat & 1) << 4) + (f & 15);
    else         orow = (size_t)f;
    *(s16x8*)(out + orow * R + (r0 + orr)) = v;
  }
}

#define SBAR() __builtin_amdgcn_s_barrier()
#define LGKM0() asm volatile("s_waitcnt lgkmcnt(0)")
#define LGKM8() asm volatile("s_waitcnt lgkmcnt(8)")
#define VMCNT6() asm volatile("s_waitcnt vmcnt(6)")
#define VMCNT3() asm volatile("s_waitcnt vmcnt(3)")
#define VMCNT0() asm volatile("s_waitcnt vmcnt(0)")

// ======== gate+up GEMM: 256x128 tile, BK=32, 3-buf LDS, 2 blocks/CU ========
// 8 waves (2M x 4N); wave = 128m x 32n: acc[8 fi][2 gi] (64 VGPR).
// LDS: sA[3][2half(=wm)][128][32], sB[3][128][32] = 72KB -> 2 blocks/CU.
// Rows are 64B (4 chunks); swizzle chunk ^= (row>>1)&3 (pre-swizzled global
// src + read addr): per-16-lane beat = 2 lanes/bank-group = free.
// 3-buffer rotation: body T reads buf b=T%3, stages tile T+2 into (T+2)%3
// (= (T-1)%3, last read 1 barrier ago -> WAR-safe). vmcnt(3) drains tile T+1,
// keeps T+2's 3 loads in flight (~2 K-tile slack). GU interleave: B-window
// rows wn*32+gi*16+rlo -> gi0=gate, gi1=up of f = nT*64+wn*16+rlo.
__global__ __launch_bounds__(512, 4) void gemm_gateup_bk32(
    const u16* __restrict__ A, const u16* __restrict__ Bl,
    const u16* __restrict__ Bv, const int* __restrict__ tt,
    u16* __restrict__ H, int* __restrict__ qcnt) {
  __shared__ u16 sA[3][2][128][32];  // 48KB
  __shared__ u16 sB[3][128][32];     // 24KB
  __shared__ int sQ;

  const int t = threadIdx.x;
  const int lane = t & 63;
  const int rlo = lane & 15;
  const int hi = lane >> 4;
  const int wn = (t >> 6) & 3;
  const int wm = (t >> 8) & 1;

  const int rowq = t >> 2;  // 0..127 staging row
  const int gsw = ((t & 3) ^ ((rowq >> 1) & 3)) << 4;
  char* ldsA = (char*)&sA[0][0][0][0];
  char* ldsB = (char*)&sB[0][0][0];
  const int woff = (t >> 6) << 10;  // wave-uniform 1KB LDS base

  const int cx = (hi ^ ((rlo >> 1) & 3)) << 4;
  const int aoff = wm * 8192 + rlo * 64 + cx;  // + b*16384 + fi*1024
  const int boff = wn * 2048 + rlo * 64 + cx;  // + b*8192  + gi*1024

  s16x8 af[4], bf[2];
  f32x4 acc[8][2];
  const f32x4 z = {0.f, 0.f, 0.f, 0.f};

#define GSTG(bv, kt)                                                           \
  do {                                                                         \
    GLOAD16(srcA + (kt) * 64, ldsA + (bv) * 16384 + woff);                     \
    GLOAD16(srcA + 1048576 + (kt) * 64, ldsA + (bv) * 16384 + 8192 + woff);    \
    GLOAD16(srcB + (kt) * 64, ldsB + (bv) * 8192 + woff);                      \
  } while (0)
#define GLDA(bv, mh)                                                           \
  do {                                                                         \
    _Pragma("unroll") for (int fi = 0; fi < 4; ++fi)                           \
        af[fi] = *(const s16x8*)(ldsA + (bv) * 16384 + aoff +                  \
                                 (mh) * 4096 + fi * 1024);                     \
  } while (0)
#define GLDB(bv)                                                               \
  do {                                                                         \
    bf[0] = *(const s16x8*)(ldsB + (bv) * 8192 + boff);                        \
    bf[1] = *(const s16x8*)(ldsB + (bv) * 8192 + boff + 1024);                 \
  } while (0)
#define GMFMA(mh)                                                              \
  do {                                                                         \
    __builtin_amdgcn_s_setprio(1);                                             \
    _Pragma("unroll") for (int fi = 0; fi < 4; ++fi)                           \
        _Pragma("unroll") for (int gi = 0; gi < 2; ++gi)                       \
        acc[(mh)*4 + fi][gi] = __builtin_amdgcn_mfma_f32_16x16x32_bf16(        \
            af[fi], bf[gi], acc[(mh)*4 + fi][gi], 0, 0, 0);                    \
    __builtin_amdgcn_s_setprio(0);                                             \
  } while (0)

  for (;;) {
    __syncthreads();
    if (t == 0) sQ = atomicAdd(qcnt, 1);
    __syncthreads();
    const int q = sQ;
    if (q >= 2752) break;
    const int nT = q >> 4;   // 0..171 (64-f windows)
    const int mT = q & 15;
    const int side = tt[mT << 8];
    const u16* GU = side ? Bl : Bv;
    const char* srcA = (const char*)A + (size_t)(mT * 256 + rowq) * 8192 + gsw;
    const char* srcB = (const char*)GU + (size_t)(nT * 128 + rowq) * 8192 + gsw;

#pragma unroll
    for (int i = 0; i < 8; ++i) { acc[i][0] = z; acc[i][1] = z; }

    // prologue: tiles 0,1 -> bufs 0,1; drain tile0 (keep tile1's 3 in flight)
    GSTG(0, 0); GSTG(1, 1);
    VMCNT3();
    SBAR();

    int b = 0, b2 = 2;
    for (int T = 0; T < 126; ++T) {
      // P1: A-lo + B frags | stage tile T+2 -> b2
      GLDA(b, 0); GLDB(b);
      GSTG(b2, T + 2);
      SBAR(); LGKM0(); GMFMA(0); SBAR();
      // P2: A-hi frags | checkpoint (drain tile T+1)
      GLDA(b, 1);
      SBAR(); LGKM0(); GMFMA(1);
      VMCNT3(); SBAR();
      b = (b == 2) ? 0 : b + 1;
      b2 = (b2 == 2) ? 0 : b2 + 1;
    }
    // T=126 (buf 0): no stage; drain tile 127 fully
    GLDA(0, 0); GLDB(0);
    SBAR(); LGKM0(); GMFMA(0); SBAR();
    GLDA(0, 1);
    SBAR(); LGKM0(); GMFMA(1);
    VMCNT0(); SBAR();
    // T=127 (buf 1)
    GLDA(1, 0); GLDB(1);
    SBAR(); LGKM0(); GMFMA(0); SBAR();
    GLDA(1, 1);
    SBAR(); LGKM0(); GMFMA(1);

    // epilogue: silu(gate)*up -> H ; f = nT*64 + wn*16 + rlo
    const int f = nT * 64 + wn * 16 + rlo;
#pragma unroll
    for (int fi = 0; fi < 8; ++fi) {
      const int row0 = mT * 256 + wm * 128 + fi * 16 + hi * 4;
#pragma unroll
      for (int r = 0; r < 4; ++r) {
        const float gv = acc[fi][0][r];
        const float uv = acc[fi][1][r];
        const float hv = gv / (1.f + __expf(-gv)) * uv;
        H[(size_t)(row0 + r) * 11008 + f] = f2bf(hv);
      }
    }
  }
#undef GSTG
#undef GLDA
#undef GLDB
#undef GMFMA
}

// ---------------- down GEMM (R12 verbatim: frag-once 8-phase 256x256) -------
__global__ __launch_bounds__(512, 1) void gemm_down(
    const u16* __restrict__ A, const u16* __restrict__ Bl,
    const u16* __restrict__ Bv, const int* __restrict__ tt,
    float* __restrict__ O) {
  constexpr int KB = 22016;
  constexpr int NK = KB / 128;  // 172
  __shared__ u16 sA[2][2][128][64];
  __shared__ u16 sB[2][2][128][64];

  const int bid = blockIdx.x;
  const int wg = (bid & 7) * 32 + (bid >> 3);
  const int mT = wg & 15;
  const int nT = wg >> 4;

  const int t = threadIdx.x;
  const int lane = t & 63;
  const int rlo = lane & 15;
  const int hi = lane >> 4;
  const int wn = (t >> 6) & 3;
  const int wm = (t >> 8) & 1;

  const int side = tt[mT << 8];
  const u16* B = side ? Bl : Bv;

  const int rowq = t >> 3;
  const int gsw = ((t & 7) ^ (rowq & 7)) << 4;
  const char* srcA = (const char*)A + (size_t)(mT * 256 + rowq) * KB + gsw;
  const char* srcB = (const char*)B + (size_t)(nT * 256 + rowq) * KB + gsw;
  char* ldsA = (char*)&sA[0][0][0][0];
  char* ldsB = (char*)&sB[0][0][0][0];
  const int woff = (t & 448) << 4;

#define STG_A(d, h, kt)                                                        \
  do {                                                                         \
    GLOAD16(srcA + (size_t)((h) * 128) * KB + (kt) * 128,                      \
            ldsA + (d) * 32768 + (h) * 16384 + woff);                          \
    GLOAD16(srcA + (size_t)((h) * 128 + 64) * KB + (kt) * 128,                 \
            ldsA + (d) * 32768 + (h) * 16384 + 8192 + woff);                   \
  } while (0)
#define STG_B(d, h, kt)                                                        \
  do {                                                                         \
    GLOAD16(srcB + (size_t)((h) * 128) * KB + (kt) * 128,                      \
            ldsB + (d) * 32768 + (h) * 16384 + woff);                          \
    GLOAD16(srcB + (size_t)((h) * 128 + 64) * KB + (kt) * 128,                 \
            ldsB + (d) * 32768 + (h) * 16384 + 8192 + woff);                   \
  } while (0)

  const int cxa = (hi ^ (rlo & 7)) << 4;
  const int cxb = ((4 + hi) ^ (rlo & 7)) << 4;
  const int arow = (wm * 64 + rlo) * 128;
  const int brow = (wn * 32 + rlo) * 128;

  s16x8 af[4][2], bf[2][2][2];
  f32x4 acc[8][4];
  const f32x4 z = {0.f, 0.f, 0.f, 0.f};
#pragma unroll
  for (int i = 0; i < 8; ++i)
#pragma unroll
    for (int j = 0; j < 4; ++j) acc[i][j] = z;

#define LDA(d, mh)                                                             \
  do {                                                                         \
    _Pragma("unroll") for (int fi = 0; fi < 4; ++fi) {                         \
      const char* p = ldsA + (d) * 32768 + (mh) * 16384 + arow + fi * 2048;    \
      af[fi][0] = *(const s16x8*)(p + cxa);                                    \
      af[fi][1] = *(const s16x8*)(p + cxb);                                    \
    }                                                                          \
  } while (0)
#define LDBS(bi, d, nh)                                                        \
  do {                                                                         \
    _Pragma("unroll") for (int gi = 0; gi < 2; ++gi) {                         \
      const char* p = ldsB + (d) * 32768 + (nh) * 16384 + brow + gi * 2048;    \
      bf[bi][gi][0] = *(const s16x8*)(p + cxa);                                \
      bf[bi][gi][1] = *(const s16x8*)(p + cxb);                                \
    }                                                                          \
  } while (0)
#define MFMA16(mh, nh)                                                         \
  do {                                                                         \
    __builtin_amdgcn_s_setprio(1);                                             \
    _Pragma("unroll") for (int fi = 0; fi < 4; ++fi)                           \
        _Pragma("unroll") for (int gi = 0; gi < 2; ++gi) {                     \
      acc[(mh)*4 + fi][(nh)*2 + gi] = __builtin_amdgcn_mfma_f32_16x16x32_bf16( \
          af[fi][0], bf[nh][gi][0], acc[(mh)*4 + fi][(nh)*2 + gi], 0, 0, 0);   \
      acc[(mh)*4 + fi][(nh)*2 + gi] = __builtin_amdgcn_mfma_f32_16x16x32_bf16( \
          af[fi][1], bf[nh][gi][1], acc[(mh)*4 + fi][(nh)*2 + gi], 0, 0, 0);   \
    }                                                                          \
    __builtin_amdgcn_s_setprio(0);                                             \
  } while (0)

  STG_A(0, 0, 0); STG_B(0, 0, 0); STG_B(0, 1, 0); STG_A(0, 1, 0);
  STG_A(1, 0, 1); STG_B(1, 0, 1); STG_B(1, 1, 1);
  VMCNT6();
  SBAR();

  for (int T = 0; T < NK - 2; T += 2) {
    LDA(0, 0); LDBS(0, 0, 0);
    STG_A(1, 1, T + 1);
    LGKM8();
    SBAR(); LGKM0(); MFMA16(0, 0); SBAR();
    LDBS(1, 0, 1);
    STG_A(0, 0, T + 2);
    SBAR(); LGKM0(); MFMA16(0, 1); SBAR();
    LDA(0, 1);
    STG_B(0, 0, T + 2);
    SBAR(); LGKM0(); MFMA16(1, 1); SBAR();
    STG_B(0, 1, T + 2);
    VMCNT6();
    SBAR(); MFMA16(1, 0); SBAR();
    LDA(1, 0); LDBS(0, 1, 0);
    STG_A(0, 1, T + 2);
    LGKM8();
    SBAR(); LGKM0(); MFMA16(0, 0); SBAR();
    LDBS(1, 1, 1);
    STG_A(1, 0, T + 3);
    SBAR(); LGKM0(); MFMA16(0, 1); SBAR();
    LDA(1, 1);
    STG_B(1, 0, T + 3);
    SBAR(); LGKM0(); MFMA16(1, 1); SBAR();
    STG_B(1, 1, T + 3);
    VMCNT6();
    SBAR(); MFMA16(1, 0); SBAR();
  }
  {
    LDA(0, 0); LDBS(0, 0, 0);
    STG_A(1, 1, NK - 1);
    LGKM8();
    SBAR(); LGKM0(); MFMA16(0, 0); SBAR();
    LDBS(1, 0, 1);
    SBAR(); LGKM0(); MFMA16(0, 1); SBAR();
    LDA(0, 1);
    SBAR(); LGKM0(); MFMA16(1, 1); SBAR();
    VMCNT0();
    SBAR(); MFMA16(1, 0); SBAR();
    LDA(1, 0); LDBS(0, 1, 0);
    LGKM8();
    SBAR(); LGKM0(); MFMA16(0, 0); SBAR();
    LDBS(1, 1, 1);
    SBAR(); LGKM0(); MFMA16(0, 1); SBAR();
    LDA(1, 1);
    SBAR(); LGKM0(); MFMA16(1, 1); SBAR();
    MFMA16(1, 0);
  }

#pragma unroll
  for (int mh = 0; mh < 2; ++mh)
#pragma unroll
    for (int fi = 0; fi < 4; ++fi) {
      const int row0 = mT * 256 + mh * 128 + wm * 64 + fi * 16 + hi * 4;
#pragma unroll
      for (int nh = 0; nh < 2; ++nh)
#pragma unroll
        for (int gi = 0; gi < 2; ++gi) {
          const int col = nT * 256 + nh * 128 + wn * 32 + gi * 16 + rlo;
          const f32x4 a = acc[mh * 4 + fi][nh * 2 + gi];
#pragma unroll
          for (int r = 0; r < 4; ++r)
            O[(size_t)(row0 + r) * 4096 + col] = a[r];
        }
    }
#undef STG_A
#undef STG_B
#undef LDA
#undef LDBS
#undef MFMA16
}

extern "C" void kernel_launch(void* const* d_in, const int* in_sizes, int n_in,
                              void* d_out, int out_size, void* d_ws, size_t ws_size,
                              hipStream_t stream) {
  (void)in_sizes; (void)n_in; (void)out_size; (void)ws_size;
  const float* x  = (const float*)d_in[0];
  const int*   tt = (const int*)d_in[1];
  const float* lg = (const float*)d_in[2];
  const float* lu = (const float*)d_in[3];
  const float* ld = (const float*)d_in[4];
  const float* vg = (const float*)d_in[5];
  const float* vu = (const float*)d_in[6];
  const float* vd = (const float*)d_in[7];

  u16* ws  = (u16*)d_ws;
  u16* xbf = ws;                        // 4096*4096            = 16,777,216
  u16* GUl = xbf + 16777216;            // 22016*4096           = 90,177,536
  u16* GUv = GUl + 90177536;
  u16* ldT = GUv + 90177536;            // 4096*11008           = 45,088,768
  u16* vdT = ldT + 45088768;
  u16* hbuf = vdT + 45088768;           // 4096*11008
  int* qcnt = (int*)(hbuf + 45088768);  // 4-byte work-queue counter
  // total: ~665 MB + 4 B

  (void)hipMemsetAsync(qcnt, 0, 4, stream);
  prep_kernel<<<dim3(11008, 7), dim3(256), 0, stream>>>(
      lg, lu, vg, vu, ld, vd, x, GUl, GUv, ldT, vdT, xbf);
  gemm_gateup_bk32<<<dim3(512), dim3(512), 0, stream>>>(
      xbf, GUl, GUv, tt, hbuf, qcnt);
  gemm_down<<<dim3(256), dim3(512), 0, stream>>>(hbuf, ldT, vdT, tt, (float*)d_out);
}

// Round 16
// 1368.559 us; speedup vs baseline: 1.0646x; 1.0646x over previous
//
#include <hip/hip_runtime.h>
#include <math.h>

typedef unsigned short u16;
typedef short s16x8 __attribute__((ext_vector_type(8)));
typedef float f32x4 __attribute__((ext_vector_type(4)));

#define GLOAD16(gp, lp)                                                        \
  __builtin_amdgcn_global_load_lds(                                            \
      (const __attribute__((address_space(1))) void*)(gp),                     \
      (__attribute__((address_space(3))) void*)(lp), 16, 0, 0)

__device__ __forceinline__ u16 f2bf(float f) {
  union { float f; unsigned u; } v; v.f = f;
  unsigned r = v.u + 0x7fffu + ((v.u >> 16) & 1u);  // RNE
  return (u16)(r >> 16);
}

// ------- kernel A: transpose+cvt (y=0..5) + x cvt (y=6). (R10 verbatim)
__global__ __launch_bounds__(256) void prep_kernel(
    const float* __restrict__ in0, const float* __restrict__ in1,
    const float* __restrict__ in2, const float* __restrict__ in3,
    const float* __restrict__ in4, const float* __restrict__ in5,
    const float* __restrict__ xin,
    u16* __restrict__ o01, u16* __restrict__ o23,
    u16* __restrict__ o4, u16* __restrict__ o5, u16* __restrict__ xout) {
  const int mat = blockIdx.y;
  const int t = threadIdx.x;
  if (mat == 6) {
    if (blockIdx.x >= 8192) return;
    size_t i = ((size_t)blockIdx.x * 256 + t) * 8;
    float4 a = *(const float4*)(xin + i);
    float4 b = *(const float4*)(xin + i + 4);
    s16x8 v;
    v[0] = (short)f2bf(a.x); v[1] = (short)f2bf(a.y);
    v[2] = (short)f2bf(a.z); v[3] = (short)f2bf(a.w);
    v[4] = (short)f2bf(b.x); v[5] = (short)f2bf(b.y);
    v[6] = (short)f2bf(b.z); v[7] = (short)f2bf(b.w);
    *(s16x8*)(xout + i) = v;
    return;
  }
  __shared__ float s[64 * 65];
  const float* in; u16* out;
  switch (mat) {
    case 0: in = in0; out = o01; break;
    case 1: in = in1; out = o01; break;
    case 2: in = in2; out = o23; break;
    case 3: in = in3; out = o23; break;
    case 4: in = in4; out = o4; break;
    default: in = in5; out = o5; break;
  }
  const int R = (mat < 4) ? 4096 : 11008;
  const int C = (mat < 4) ? 11008 : 4096;
  const int nTc = C >> 6;
  const int tr = blockIdx.x / nTc, tc = blockIdx.x - tr * nTc;
  const int r0 = tr << 6, c0 = tc << 6;
#pragma unroll
  for (int p = 0; p < 4; ++p) {
    const int lr = p * 16 + (t >> 4);
    const int lc = (t & 15) * 4;
    float4 v = *(const float4*)(in + (size_t)(r0 + lr) * C + (c0 + lc));
    float* sp = &s[lr * 65 + lc];
    sp[0] = v.x; sp[1] = v.y; sp[2] = v.z; sp[3] = v.w;
  }
  __syncthreads();
#pragma unroll
  for (int q = 0; q < 2; ++q) {
    const int oc = q * 32 + (t >> 3);
    const int orr = (t & 7) * 8;
    s16x8 v;
#pragma unroll
    for (int i = 0; i < 8; ++i) v[i] = (short)f2bf(s[(orr + i) * 65 + oc]);
    const int f = c0 + oc;
    size_t orow;
    if (mat < 4) orow = (size_t)((f >> 4) << 5) + ((mat & 1) << 4) + (f & 15);
    else         orow = (size_t)f;
    *(s16x8*)(out + orow * R + (r0 + orr)) = v;
  }
}

#define SBAR() __builtin_amdgcn_s_barrier()
#define LGKM0() asm volatile("s_waitcnt lgkmcnt(0)")
#define LGKM8() asm volatile("s_waitcnt lgkmcnt(8)")
#define VMCNT6() asm volatile("s_waitcnt vmcnt(6)")
#define VMCNT0() asm volatile("s_waitcnt vmcnt(0)")

// ---------------- persistent gate+up GEMM + silu fusion ----------------
// R10 static XCD-aligned mapping + R5 frag-once 8-phase core + 3-DEEP B
// PIPELINE (sB[3]=96KB + sA[2]=64KB = 160KB LDS). B staged 3-4 K-tiles ahead
// (~10 phases) to cover HBM streaming latency of the 720MB GU weights.
// FIX vs R15: the final pair must have A-h1(FK-1) staged — done at the
// special iteration's P8 (WAR-safe: sA[1]h1 last read at P7; RAW-safe:
// VMCNT0 after the stage drains it).
__global__ __launch_bounds__(512, 1) void gemm_gateup_persist(
    const u16* __restrict__ A, const u16* __restrict__ Bl,
    const u16* __restrict__ Bv, const int* __restrict__ tt,
    u16* __restrict__ H) {
  __shared__ u16 sA[2][2][128][64];   // 64 KB
  __shared__ u16 sB[3][2][128][64];   // 96 KB

  const int bid = blockIdx.x;
  const int c = ((bid >> 7) << 3) | (bid & 7);
  const int mT = (bid >> 3) & 15;
  const int ntiles = (c < 6) ? 6 : 5;
  const int FK = ntiles * 64;

  const int t = threadIdx.x;
  const int lane = t & 63;
  const int rlo = lane & 15;
  const int hi = lane >> 4;
  const int wn = (t >> 6) & 3;
  const int wm = (t >> 8) & 1;

  const int side = tt[mT << 8];
  const u16* B = side ? Bl : Bv;

  const int rowq = t >> 3;
  const int gsw = ((t & 7) ^ (rowq & 7)) << 4;
  const char* srcA = (const char*)A + (size_t)(mT * 256 + rowq) * 8192 + gsw;
  const char* srcB0 = (const char*)B + ((size_t)(c * 256) + rowq) * 8192 + gsw;
  char* ldsA = (char*)&sA[0][0][0][0];
  char* ldsB = (char*)&sB[0][0][0][0];
  const int woff = (t & 448) << 4;

#define PSTG_A(d, h, q)                                                        \
  do {                                                                         \
    const char* _pa = srcA + ((q) & 63) * 128;                                 \
    GLOAD16(_pa + (size_t)((h) * 128) * 8192,                                  \
            ldsA + (d) * 32768 + (h) * 16384 + woff);                          \
    GLOAD16(_pa + (size_t)((h) * 128 + 64) * 8192,                             \
            ldsA + (d) * 32768 + (h) * 16384 + 8192 + woff);                   \
  } while (0)
#define PSTG_B(boffB, h, q)                                                    \
  do {                                                                         \
    const char* _pb = srcB0 + (size_t)((q) >> 6) * 33554432 +                  \
                      (size_t)((h) * 128) * 8192 + ((q) & 63) * 128;           \
    GLOAD16(_pb, ldsB + (boffB) + (h) * 16384 + woff);                         \
    GLOAD16(_pb + (size_t)64 * 8192,                                           \
            ldsB + (boffB) + (h) * 16384 + 8192 + woff);                       \
  } while (0)

  const int cxa = (hi ^ (rlo & 7)) << 4;
  const int cxb = ((4 + hi) ^ (rlo & 7)) << 4;
  const int arow = (wm * 64 + rlo) * 128;
  const int brow = (wn * 32 + rlo) * 128;

  s16x8 af[4][2], bf[2][2][2];  // bf[nh-set][gi][ks] resident across P1..P4
  f32x4 acc[8][4];
  const f32x4 z = {0.f, 0.f, 0.f, 0.f};
#pragma unroll
  for (int i = 0; i < 8; ++i)
#pragma unroll
    for (int j = 0; j < 4; ++j) acc[i][j] = z;

#define LDA(d, mh)                                                             \
  do {                                                                         \
    _Pragma("unroll") for (int fi = 0; fi < 4; ++fi) {                         \
      const char* p = ldsA + (d) * 32768 + (mh) * 16384 + arow + fi * 2048;    \
      af[fi][0] = *(const s16x8*)(p + cxa);                                    \
      af[fi][1] = *(const s16x8*)(p + cxb);                                    \
    }                                                                          \
  } while (0)
#define LDBS(bi, boffB, nh)                                                    \
  do {                                                                         \
    _Pragma("unroll") for (int gi = 0; gi < 2; ++gi) {                         \
      const char* p = ldsB + (boffB) + (nh) * 16384 + brow + gi * 2048;        \
      bf[bi][gi][0] = *(const s16x8*)(p + cxa);                                \
      bf[bi][gi][1] = *(const s16x8*)(p + cxb);                                \
    }                                                                          \
  } while (0)
#define MFMA16(mh, nh)                                                         \
  do {                                                                         \
    __builtin_amdgcn_s_setprio(1);                                             \
    _Pragma("unroll") for (int fi = 0; fi < 4; ++fi)                           \
        _Pragma("unroll") for (int gi = 0; gi < 2; ++gi) {                     \
      acc[(mh)*4 + fi][(nh)*2 + gi] = __builtin_amdgcn_mfma_f32_16x16x32_bf16( \
          af[fi][0], bf[nh][gi][0], acc[(mh)*4 + fi][(nh)*2 + gi], 0, 0, 0);   \
      acc[(mh)*4 + fi][(nh)*2 + gi] = __builtin_amdgcn_mfma_f32_16x16x32_bf16( \
          af[fi][1], bf[nh][gi][1], acc[(mh)*4 + fi][(nh)*2 + gi], 0, 0, 0);   \
    }                                                                          \
    __builtin_amdgcn_s_setprio(0);                                             \
  } while (0)

#define GU_EPI(nTv)                                                            \
  do {                                                                         \
    const int _nT = (nTv);                                                     \
    _Pragma("unroll") for (int mh = 0; mh < 2; ++mh)                           \
        _Pragma("unroll") for (int fi = 0; fi < 4; ++fi) {                     \
      const int row0 = mT * 256 + mh * 128 + wm * 64 + fi * 16 + hi * 4;       \
      _Pragma("unroll") for (int nh = 0; nh < 2; ++nh) {                       \
        const int fc = _nT * 128 + (nh * 4 + wn) * 16 + rlo;                   \
        const f32x4 g = acc[mh * 4 + fi][nh * 2 + 0];                          \
        const f32x4 u = acc[mh * 4 + fi][nh * 2 + 1];                          \
        _Pragma("unroll") for (int r = 0; r < 4; ++r) {                        \
          const float gv = g[r];                                               \
          const float hv = gv / (1.f + __expf(-gv)) * u[r];                    \
          H[(size_t)(row0 + r) * 11008 + fc] = f2bf(hv);                       \
        }                                                                      \
      }                                                                        \
    }                                                                          \
  } while (0)

  // prologue: A(0) full, A0(1); B(0), B(1), B(2) -> buffers 0,1,2
  PSTG_A(0, 0, 0); PSTG_B(0, 0, 0); PSTG_B(0, 1, 0); PSTG_A(0, 1, 0);
  PSTG_A(1, 0, 1); PSTG_B(32768, 0, 1); PSTG_B(32768, 1, 1);
  PSTG_B(65536, 0, 2); PSTG_B(65536, 1, 2);
  VMCNT6();
  SBAR();

  int bB0 = 0, bB1 = 32768, bB2 = 65536;  // bB_i holds B(T+i)
  for (int T = 0; T < FK - 4; T += 2) {
    // P1: af(mh0), bf0<-bB0 | stage A-h1(T+1)
    LDA(0, 0); LDBS(0, bB0, 0);
    PSTG_A(1, 1, T + 1);
    LGKM8();
    SBAR(); LGKM0(); MFMA16(0, 0); SBAR();
    // P2: bf1<-bB0 | stage A-h0(T+2)
    LDBS(1, bB0, 1);
    PSTG_A(0, 0, T + 2);
    SBAR(); LGKM0(); MFMA16(0, 1); SBAR();
    // P3: af(mh1) | stage B-h0(T+3)->bB0 slot (B(T) reads done @P2)
    LDA(0, 1);
    PSTG_B(bB0, 0, T + 3);
    SBAR(); LGKM0(); MFMA16(1, 1); SBAR();
    // P4: stage B-h1(T+3) | checkpoint
    PSTG_B(bB0, 1, T + 3);
    VMCNT6();
    SBAR(); MFMA16(1, 0); SBAR();
    // P5: buf1 af(mh0), bf0<-bB1 | stage A-h1(T+2)
    LDA(1, 0); LDBS(0, bB1, 0);
    PSTG_A(0, 1, T + 2);
    LGKM8();
    SBAR(); LGKM0(); MFMA16(0, 0); SBAR();
    // P6: bf1<-bB1 | stage A-h0(T+3)
    LDBS(1, bB1, 1);
    PSTG_A(1, 0, T + 3);
    SBAR(); LGKM0(); MFMA16(0, 1); SBAR();
    // P7: af(mh1) | stage B-h0(T+4)->bB1 slot
    LDA(1, 1);
    PSTG_B(bB1, 0, T + 4);
    SBAR(); LGKM0(); MFMA16(1, 1); SBAR();
    // P8: stage B-h1(T+4) | checkpoint
    PSTG_B(bB1, 1, T + 4);
    VMCNT6();
    SBAR(); MFMA16(1, 0); SBAR();

    if ((T & 63) == 62) {  // tile (T>>6) complete
      GU_EPI(c + 16 * (T >> 6));
#pragma unroll
      for (int i = 0; i < 8; ++i)
#pragma unroll
        for (int j = 0; j < 4; ++j) acc[i][j] = z;
    }
    const int btmp = bB2; bB2 = bB1; bB1 = bB0; bB0 = btmp;
  }
  // special iter T = FK-4: stage B(FK-1)@P3/P4, A-h1(FK-1)@P8; drain at P8
  {
    const int T = FK - 4;
    LDA(0, 0); LDBS(0, bB0, 0);
    PSTG_A(1, 1, T + 1);
    LGKM8();
    SBAR(); LGKM0(); MFMA16(0, 0); SBAR();
    LDBS(1, bB0, 1);
    PSTG_A(0, 0, T + 2);
    SBAR(); LGKM0(); MFMA16(0, 1); SBAR();
    LDA(0, 1);
    PSTG_B(bB0, 0, T + 3);
    SBAR(); LGKM0(); MFMA16(1, 1); SBAR();
    PSTG_B(bB0, 1, T + 3);
    VMCNT6();
    SBAR(); MFMA16(1, 0); SBAR();
    LDA(1, 0); LDBS(0, bB1, 0);
    PSTG_A(0, 1, T + 2);
    LGKM8();
    SBAR(); LGKM0(); MFMA16(0, 0); SBAR();
    LDBS(1, bB1, 1);
    PSTG_A(1, 0, T + 3);
    SBAR(); LGKM0(); MFMA16(0, 1); SBAR();
    LDA(1, 1);
    SBAR(); LGKM0(); MFMA16(1, 1); SBAR();
    PSTG_A(1, 1, T + 3);  // A-h1(FK-1): WAR-safe (sA[1]h1 last read @P7)
    VMCNT0();             // drains it (plus everything else)
    SBAR(); MFMA16(1, 0); SBAR();
    const int btmp = bB2; bB2 = bB1; bB1 = bB0; bB0 = btmp;
  }
  // final pair (K-tiles FK-2, FK-1): all data resident & drained; no barriers
  {
    LDA(0, 0); LDBS(0, bB0, 0);
    LGKM0(); MFMA16(0, 0);
    LDBS(1, bB0, 1);
    LGKM0(); MFMA16(0, 1);
    LDA(0, 1);
    LGKM0(); MFMA16(1, 1); MFMA16(1, 0);
    LDA(1, 0); LDBS(0, bB1, 0);
    LGKM0(); MFMA16(0, 0);
    LDBS(1, bB1, 1);
    LGKM0(); MFMA16(0, 1);
    LDA(1, 1);
    LGKM0(); MFMA16(1, 1); MFMA16(1, 0);
  }
  GU_EPI(c + 16 * (ntiles - 1));
#undef PSTG_A
#undef PSTG_B
#undef LDA
#undef LDBS
#undef MFMA16
#undef GU_EPI
}

// ---------------- down GEMM (R10/R12 verbatim: frag-once 8-phase) ----------
__global__ __launch_bounds__(512, 1) void gemm_down(
    const u16* __restrict__ A, const u16* __restrict__ Bl,
    const u16* __restrict__ Bv, const int* __restrict__ tt,
    float* __restrict__ O) {
  constexpr int KB = 22016;
  constexpr int NK = KB / 128;  // 172
  __shared__ u16 sA[2][2][128][64];
  __shared__ u16 sB[2][2][128][64];

  const int bid = blockIdx.x;
  const int wg = (bid & 7) * 32 + (bid >> 3);
  const int mT = wg & 15;
  const int nT = wg >> 4;

  const int t = threadIdx.x;
  const int lane = t & 63;
  const int rlo = lane & 15;
  const int hi = lane >> 4;
  const int wn = (t >> 6) & 3;
  const int wm = (t >> 8) & 1;

  const int side = tt[mT << 8];
  const u16* B = side ? Bl : Bv;

  const int rowq = t >> 3;
  const int gsw = ((t & 7) ^ (rowq & 7)) << 4;
  const char* srcA = (const char*)A + (size_t)(mT * 256 + rowq) * KB + gsw;
  const char* srcB = (const char*)B + (size_t)(nT * 256 + rowq) * KB + gsw;
  char* ldsA = (char*)&sA[0][0][0][0];
  char* ldsB = (char*)&sB[0][0][0][0];
  const int woff = (t & 448) << 4;

#define STG_A(d, h, kt)                                                        \
  do {                                                                         \
    GLOAD16(srcA + (size_t)((h) * 128) * KB + (kt) * 128,                      \
            ldsA + (d) * 32768 + (h) * 16384 + woff);                          \
    GLOAD16(srcA + (size_t)((h) * 128 + 64) * KB + (kt) * 128,                 \
            ldsA + (d) * 32768 + (h) * 16384 + 8192 + woff);                   \
  } while (0)
#define STG_B(d, h, kt)                                                        \
  do {                                                                         \
    GLOAD16(srcB + (size_t)((h) * 128) * KB + (kt) * 128,                      \
            ldsB + (d) * 32768 + (h) * 16384 + woff);                          \
    GLOAD16(srcB + (size_t)((h) * 128 + 64) * KB + (kt) * 128,                 \
            ldsB + (d) * 32768 + (h) * 16384 + 8192 + woff);                   \
  } while (0)

  const int cxa = (hi ^ (rlo & 7)) << 4;
  const int cxb = ((4 + hi) ^ (rlo & 7)) << 4;
  const int arow = (wm * 64 + rlo) * 128;
  const int brow = (wn * 32 + rlo) * 128;

  s16x8 af[4][2], bf[2][2][2];
  f32x4 acc[8][4];
  const f32x4 z = {0.f, 0.f, 0.f, 0.f};
#pragma unroll
  for (int i = 0; i < 8; ++i)
#pragma unroll
    for (int j = 0; j < 4; ++j) acc[i][j] = z;

#define LDA(d, mh)                                                             \
  do {                                                                         \
    _Pragma("unroll") for (int fi = 0; fi < 4; ++fi) {                         \
      const char* p = ldsA + (d) * 32768 + (mh) * 16384 + arow + fi * 2048;    \
      af[fi][0] = *(const s16x8*)(p + cxa);                                    \
      af[fi][1] = *(const s16x8*)(p + cxb);                                    \
    }                                                                          \
  } while (0)
#define LDBS(bi, d, nh)                                                        \
  do {                                                                         \
    _Pragma("unroll") for (int gi = 0; gi < 2; ++gi) {                         \
      const char* p = ldsB + (d) * 32768 + (nh) * 16384 + brow + gi * 2048;    \
      bf[bi][gi][0] = *(const s16x8*)(p + cxa);                                \
      bf[bi][gi][1] = *(const s16x8*)(p + cxb);                                \
    }                                                                          \
  } while (0)
#define MFMA16(mh, nh)                                                         \
  do {                                                                         \
    __builtin_amdgcn_s_setprio(1);                                             \
    _Pragma("unroll") for (int fi = 0; fi < 4; ++fi)                           \
        _Pragma("unroll") for (int gi = 0; gi < 2; ++gi) {                     \
      acc[(mh)*4 + fi][(nh)*2 + gi] = __builtin_amdgcn_mfma_f32_16x16x32_bf16( \
          af[fi][0], bf[nh][gi][0], acc[(mh)*4 + fi][(nh)*2 + gi], 0, 0, 0);   \
      acc[(mh)*4 + fi][(nh)*2 + gi] = __builtin_amdgcn_mfma_f32_16x16x32_bf16( \
          af[fi][1], bf[nh][gi][1], acc[(mh)*4 + fi][(nh)*2 + gi], 0, 0, 0);   \
    }                                                                          \
    __builtin_amdgcn_s_setprio(0);                                             \
  } while (0)

  STG_A(0, 0, 0); STG_B(0, 0, 0); STG_B(0, 1, 0); STG_A(0, 1, 0);
  STG_A(1, 0, 1); STG_B(1, 0, 1); STG_B(1, 1, 1);
  VMCNT6();
  SBAR();

  for (int T = 0; T < NK - 2; T += 2) {
    LDA(0, 0); LDBS(0, 0, 0);
    STG_A(1, 1, T + 1);
    LGKM8();
    SBAR(); LGKM0(); MFMA16(0, 0); SBAR();
    LDBS(1, 0, 1);
    STG_A(0, 0, T + 2);
    SBAR(); LGKM0(); MFMA16(0, 1); SBAR();
    LDA(0, 1);
    STG_B(0, 0, T + 2);
    SBAR(); LGKM0(); MFMA16(1, 1); SBAR();
    STG_B(0, 1, T + 2);
    VMCNT6();
    SBAR(); MFMA16(1, 0); SBAR();
    LDA(1, 0); LDBS(0, 1, 0);
    STG_A(0, 1, T + 2);
    LGKM8();
    SBAR(); LGKM0(); MFMA16(0, 0); SBAR();
    LDBS(1, 1, 1);
    STG_A(1, 0, T + 3);
    SBAR(); LGKM0(); MFMA16(0, 1); SBAR();
    LDA(1, 1);
    STG_B(1, 0, T + 3);
    SBAR(); LGKM0(); MFMA16(1, 1); SBAR();
    STG_B(1, 1, T + 3);
    VMCNT6();
    SBAR(); MFMA16(1, 0); SBAR();
  }
  {
    LDA(0, 0); LDBS(0, 0, 0);
    STG_A(1, 1, NK - 1);
    LGKM8();
    SBAR(); LGKM0(); MFMA16(0, 0); SBAR();
    LDBS(1, 0, 1);
    SBAR(); LGKM0(); MFMA16(0, 1); SBAR();
    LDA(0, 1);
    SBAR(); LGKM0(); MFMA16(1, 1); SBAR();
    VMCNT0();
    SBAR(); MFMA16(1, 0); SBAR();
    LDA(1, 0); LDBS(0, 1, 0);
    LGKM8();
    SBAR(); LGKM0(); MFMA16(0, 0); SBAR();
    LDBS(1, 1, 1);
    SBAR(); LGKM0(); MFMA16(0, 1); SBAR();
    LDA(1, 1);
    SBAR(); LGKM0(); MFMA16(1, 1); SBAR();
    MFMA16(1, 0);
  }

#pragma unroll
  for (int mh = 0; mh < 2; ++mh)
#pragma unroll
    for (int fi = 0; fi < 4; ++fi) {
      const int row0 = mT * 256 + mh * 128 + wm * 64 + fi * 16 + hi * 4;
#pragma unroll
      for (int nh = 0; nh < 2; ++nh)
#pragma unroll
        for (int gi = 0; gi < 2; ++gi) {
          const int col = nT * 256 + nh * 128 + wn * 32 + gi * 16 + rlo;
          const f32x4 a = acc[mh * 4 + fi][nh * 2 + gi];
#pragma unroll
          for (int r = 0; r < 4; ++r)
            O[(size_t)(row0 + r) * 4096 + col] = a[r];
        }
    }
#undef STG_A
#undef STG_B
#undef LDA
#undef LDBS
#undef MFMA16
}

extern "C" void kernel_launch(void* const* d_in, const int* in_sizes, int n_in,
                              void* d_out, int out_size, void* d_ws, size_t ws_size,
                              hipStream_t stream) {
  (void)in_sizes; (void)n_in; (void)out_size; (void)ws_size;
  const float* x  = (const float*)d_in[0];
  const int*   tt = (const int*)d_in[1];
  const float* lg = (const float*)d_in[2];
  const float* lu = (const float*)d_in[3];
  const float* ld = (const float*)d_in[4];
  const float* vg = (const float*)d_in[5];
  const float* vu = (const float*)d_in[6];
  const float* vd = (const float*)d_in[7];

  u16* ws  = (u16*)d_ws;
  u16* xbf = ws;                        // 4096*4096            = 16,777,216
  u16* GUl = xbf + 16777216;            // 22016*4096           = 90,177,536
  u16* GUv = GUl + 90177536;
  u16* ldT = GUv + 90177536;            // 4096*11008           = 45,088,768
  u16* vdT = ldT + 45088768;
  u16* hbuf = vdT + 45088768;           // 4096*11008
  // total: 332,398,592 u16 = ~665 MB

  prep_kernel<<<dim3(11008, 7), dim3(256), 0, stream>>>(
      lg, lu, vg, vu, ld, vd, x, GUl, GUv, ldT, vdT, xbf);
  gemm_gateup_persist<<<dim3(256), dim3(512), 0, stream>>>(
      xbf, GUl, GUv, tt, hbuf);
  gemm_down<<<dim3(256), dim3(512), 0, stream>>>(hbuf, ldT, vdT, tt, (float*)d_out);
}

// Round 18
// 1297.727 us; speedup vs baseline: 1.1227x; 1.0546x over previous
//
#include <hip/hip_runtime.h>
#include <math.h>

typedef unsigned short u16;
typedef short s16x8 __attribute__((ext_vector_type(8)));
typedef float f32x4 __attribute__((ext_vector_type(4)));

#define GLOAD16(gp, lp)                                                        \
  __builtin_amdgcn_global_load_lds(                                            \
      (const __attribute__((address_space(1))) void*)(gp),                     \
      (__attribute__((address_space(3))) void*)(lp), 16, 0, 0)

__device__ __forceinline__ u16 f2bf(float f) {
  union { float f; unsigned u; } v; v.f = f;
  unsigned r = v.u + 0x7fffu + ((v.u >> 16) & 1u);  // RNE
  return (u16)(r >> 16);
}

// ------- kernel A: transpose+cvt (y=0..5) + x cvt (y=6).
// mats 0-3 (g/u) write into interleaved GU: row = (f>>4)*32 + t*16 + (f&15).
// mats 4,5 plain transpose. y=6: x fp32->bf16 flat copy (blocks 0..8191).
__global__ __launch_bounds__(256) void prep_kernel(
    const float* __restrict__ in0, const float* __restrict__ in1,
    const float* __restrict__ in2, const float* __restrict__ in3,
    const float* __restrict__ in4, const float* __restrict__ in5,
    const float* __restrict__ xin,
    u16* __restrict__ o01, u16* __restrict__ o23,
    u16* __restrict__ o4, u16* __restrict__ o5, u16* __restrict__ xout) {
  const int mat = blockIdx.y;
  const int t = threadIdx.x;
  if (mat == 6) {  // x conversion: 8192 blocks x 2048 elems
    if (blockIdx.x >= 8192) return;
    size_t i = ((size_t)blockIdx.x * 256 + t) * 8;
    float4 a = *(const float4*)(xin + i);
    float4 b = *(const float4*)(xin + i + 4);
    s16x8 v;
    v[0] = (short)f2bf(a.x); v[1] = (short)f2bf(a.y);
    v[2] = (short)f2bf(a.z); v[3] = (short)f2bf(a.w);
    v[4] = (short)f2bf(b.x); v[5] = (short)f2bf(b.y);
    v[6] = (short)f2bf(b.z); v[7] = (short)f2bf(b.w);
    *(s16x8*)(xout + i) = v;
    return;
  }
  __shared__ float s[64 * 65];
  const float* in; u16* out;
  switch (mat) {
    case 0: in = in0; out = o01; break;
    case 1: in = in1; out = o01; break;
    case 2: in = in2; out = o23; break;
    case 3: in = in3; out = o23; break;
    case 4: in = in4; out = o4; break;
    default: in = in5; out = o5; break;
  }
  const int R = (mat < 4) ? 4096 : 11008;   // input rows = output stride
  const int C = (mat < 4) ? 11008 : 4096;   // input cols
  const int nTc = C >> 6;
  const int tr = blockIdx.x / nTc, tc = blockIdx.x - tr * nTc;
  const int r0 = tr << 6, c0 = tc << 6;
#pragma unroll
  for (int p = 0; p < 4; ++p) {
    const int lr = p * 16 + (t >> 4);
    const int lc = (t & 15) * 4;
    float4 v = *(const float4*)(in + (size_t)(r0 + lr) * C + (c0 + lc));
    float* sp = &s[lr * 65 + lc];
    sp[0] = v.x; sp[1] = v.y; sp[2] = v.z; sp[3] = v.w;
  }
  __syncthreads();
#pragma unroll
  for (int q = 0; q < 2; ++q) {
    const int oc = q * 32 + (t >> 3);
    const int orr = (t & 7) * 8;
    s16x8 v;
#pragma unroll
    for (int i = 0; i < 8; ++i) v[i] = (short)f2bf(s[(orr + i) * 65 + oc]);
    const int f = c0 + oc;
    size_t orow;
    if (mat < 4) orow = (size_t)((f >> 4) << 5) + ((mat & 1) << 4) + (f & 15);
    else         orow = (size_t)f;
    *(s16x8*)(out + orow * R + (r0 + orr)) = v;
  }
}

// ======== 8-phase 256x256 GEMM, frag-once schedule ==========================
// HARDENED (R18): checkpoints use vmcnt(4) — every staged half is guaranteed
// landed >=2 phases (>=3 barriers) before its first reader (was 1 barrier).
#define SBAR() __builtin_amdgcn_s_barrier()
#define LGKM0() asm volatile("s_waitcnt lgkmcnt(0)")
#define LGKM8() asm volatile("s_waitcnt lgkmcnt(8)")
#define VMCNT4() asm volatile("s_waitcnt vmcnt(4)")
#define VMCNT0() asm volatile("s_waitcnt vmcnt(0)")

// ---------------- persistent gate+up GEMM + silu fusion ----------------
// Static XCD-aligned mapping: 16 same-c blocks on one XCD share each B panel;
// mT pinned per block -> A panel L2-resident; seamless flat-K walk with
// in-pipeline epilogue.
__global__ __launch_bounds__(512, 1) void gemm_gateup_persist(
    const u16* __restrict__ A, const u16* __restrict__ Bl,
    const u16* __restrict__ Bv, const int* __restrict__ tt,
    u16* __restrict__ H) {
  __shared__ u16 sA[2][2][128][64];
  __shared__ u16 sB[2][2][128][64];

  const int bid = blockIdx.x;
  const int c = ((bid >> 7) << 3) | (bid & 7);
  const int mT = (bid >> 3) & 15;
  const int ntiles = (c < 6) ? 6 : 5;
  const int FK = ntiles * 64;

  const int t = threadIdx.x;
  const int lane = t & 63;
  const int rlo = lane & 15;
  const int hi = lane >> 4;
  const int wn = (t >> 6) & 3;
  const int wm = (t >> 8) & 1;

  const int side = tt[mT << 8];
  const u16* B = side ? Bl : Bv;

  const int rowq = t >> 3;
  const int gsw = ((t & 7) ^ (rowq & 7)) << 4;
  const char* srcA = (const char*)A + (size_t)(mT * 256 + rowq) * 8192 + gsw;
  const char* srcB0 = (const char*)B + ((size_t)(c * 256) + rowq) * 8192 + gsw;
  char* ldsA = (char*)&sA[0][0][0][0];
  char* ldsB = (char*)&sB[0][0][0][0];
  const int woff = (t & 448) << 4;

#define PSTG_A(d, h, q)                                                        \
  do {                                                                         \
    const char* _pa = srcA + ((q) & 63) * 128;                                 \
    GLOAD16(_pa + (size_t)((h) * 128) * 8192,                                  \
            ldsA + (d) * 32768 + (h) * 16384 + woff);                          \
    GLOAD16(_pa + (size_t)((h) * 128 + 64) * 8192,                             \
            ldsA + (d) * 32768 + (h) * 16384 + 8192 + woff);                   \
  } while (0)
#define PSTG_B(d, h, q)                                                        \
  do {                                                                         \
    const char* _pb = srcB0 + (size_t)((q) >> 6) * 33554432 +                  \
                      (size_t)((h) * 128) * 8192 + ((q) & 63) * 128;           \
    GLOAD16(_pb, ldsB + (d) * 32768 + (h) * 16384 + woff);                     \
    GLOAD16(_pb + (size_t)64 * 8192,                                           \
            ldsB + (d) * 32768 + (h) * 16384 + 8192 + woff);                   \
  } while (0)

  const int cxa = (hi ^ (rlo & 7)) << 4;
  const int cxb = ((4 + hi) ^ (rlo & 7)) << 4;
  const int arow = (wm * 64 + rlo) * 128;
  const int brow = (wn * 32 + rlo) * 128;

  s16x8 af[4][2], bf[2][2][2];  // bf[nh-set][gi][ks] resident across P1..P4
  f32x4 acc[8][4];
  const f32x4 z = {0.f, 0.f, 0.f, 0.f};
#pragma unroll
  for (int i = 0; i < 8; ++i)
#pragma unroll
    for (int j = 0; j < 4; ++j) acc[i][j] = z;

#define LDA(d, mh)                                                             \
  do {                                                                         \
    _Pragma("unroll") for (int fi = 0; fi < 4; ++fi) {                         \
      const char* p = ldsA + (d) * 32768 + (mh) * 16384 + arow + fi * 2048;    \
      af[fi][0] = *(const s16x8*)(p + cxa);                                    \
      af[fi][1] = *(const s16x8*)(p + cxb);                                    \
    }                                                                          \
  } while (0)
#define LDBS(bi, d, nh)                                                        \
  do {                                                                         \
    _Pragma("unroll") for (int gi = 0; gi < 2; ++gi) {                         \
      const char* p = ldsB + (d) * 32768 + (nh) * 16384 + brow + gi * 2048;    \
      bf[bi][gi][0] = *(const s16x8*)(p + cxa);                                \
      bf[bi][gi][1] = *(const s16x8*)(p + cxb);                                \
    }                                                                          \
  } while (0)
#define MFMA16(mh, nh)                                                         \
  do {                                                                         \
    __builtin_amdgcn_s_setprio(1);                                             \
    _Pragma("unroll") for (int fi = 0; fi < 4; ++fi)                           \
        _Pragma("unroll") for (int gi = 0; gi < 2; ++gi) {                     \
      acc[(mh)*4 + fi][(nh)*2 + gi] = __builtin_amdgcn_mfma_f32_16x16x32_bf16( \
          af[fi][0], bf[nh][gi][0], acc[(mh)*4 + fi][(nh)*2 + gi], 0, 0, 0);   \
      acc[(mh)*4 + fi][(nh)*2 + gi] = __builtin_amdgcn_mfma_f32_16x16x32_bf16( \
          af[fi][1], bf[nh][gi][1], acc[(mh)*4 + fi][(nh)*2 + gi], 0, 0, 0);   \
    }                                                                          \
    __builtin_amdgcn_s_setprio(0);                                             \
  } while (0)

#define GU_EPI(nTv)                                                            \
  do {                                                                         \
    const int _nT = (nTv);                                                     \
    _Pragma("unroll") for (int mh = 0; mh < 2; ++mh)                           \
        _Pragma("unroll") for (int fi = 0; fi < 4; ++fi) {                     \
      const int row0 = mT * 256 + mh * 128 + wm * 64 + fi * 16 + hi * 4;       \
      _Pragma("unroll") for (int nh = 0; nh < 2; ++nh) {                       \
        const int fc = _nT * 128 + (nh * 4 + wn) * 16 + rlo;                   \
        const f32x4 g = acc[mh * 4 + fi][nh * 2 + 0];                          \
        const f32x4 u = acc[mh * 4 + fi][nh * 2 + 1];                          \
        _Pragma("unroll") for (int r = 0; r < 4; ++r) {                        \
          const float gv = g[r];                                               \
          const float hv = gv / (1.f + __expf(-gv)) * u[r];                    \
          H[(size_t)(row0 + r) * 11008 + fc] = f2bf(hv);                       \
        }                                                                      \
      }                                                                        \
    }                                                                          \
  } while (0)

  // prologue: tile0 full -> buf0; tile1 {A-h0, B-h0, B-h1} -> buf1.
  // vmcnt(4) drains tile0 + A(1)h0; keeps B(1) halves (drained at P4).
  PSTG_A(0, 0, 0); PSTG_B(0, 0, 0); PSTG_B(0, 1, 0); PSTG_A(0, 1, 0);
  PSTG_A(1, 0, 1); PSTG_B(1, 0, 1); PSTG_B(1, 1, 1);
  VMCNT4();
  SBAR();

  for (int T = 0; T < FK - 2; T += 2) {
    // P1: af(mh0), bf0 | stage A-h1(T+1)->buf1
    LDA(0, 0); LDBS(0, 0, 0);
    PSTG_A(1, 1, T + 1);
    LGKM8();
    SBAR(); LGKM0(); MFMA16(0, 0); SBAR();
    // P2: bf1 | stage A-h0(T+2)->buf0
    LDBS(1, 0, 1);
    PSTG_A(0, 0, T + 2);
    SBAR(); LGKM0(); MFMA16(0, 1); SBAR();
    // P3: af(mh1) | stage B-h0(T+2)->buf0
    LDA(0, 1);
    PSTG_B(0, 0, T + 2);
    SBAR(); LGKM0(); MFMA16(1, 1); SBAR();
    // P4: no reads | stage B-h1(T+2)->buf0 | checkpoint (drains thru P2)
    PSTG_B(0, 1, T + 2);
    VMCNT4();
    SBAR(); MFMA16(1, 0); SBAR();
    // P5: buf1 af(mh0), bf0 | stage A-h1(T+2)->buf0
    LDA(1, 0); LDBS(0, 1, 0);
    PSTG_A(0, 1, T + 2);
    LGKM8();
    SBAR(); LGKM0(); MFMA16(0, 0); SBAR();
    // P6: bf1 | stage A-h0(T+3)->buf1
    LDBS(1, 1, 1);
    PSTG_A(1, 0, T + 3);
    SBAR(); LGKM0(); MFMA16(0, 1); SBAR();
    // P7: af(mh1) | stage B-h0(T+3)->buf1
    LDA(1, 1);
    PSTG_B(1, 0, T + 3);
    SBAR(); LGKM0(); MFMA16(1, 1); SBAR();
    // P8: no reads | stage B-h1(T+3)->buf1 | checkpoint (drains thru P6)
    PSTG_B(1, 1, T + 3);
    VMCNT4();
    SBAR(); MFMA16(1, 0); SBAR();

    if ((T & 63) == 62) {  // tile (T>>6) complete
      GU_EPI(c + 16 * (T >> 6));
#pragma unroll
      for (int i = 0; i < 8; ++i)
#pragma unroll
        for (int j = 0; j < 4; ++j) acc[i][j] = z;
    }
  }
  // tail pair (tiles FK-2, FK-1): P1 stages the last half; drain at P4
  {
    LDA(0, 0); LDBS(0, 0, 0);
    PSTG_A(1, 1, FK - 1);
    LGKM8();
    SBAR(); LGKM0(); MFMA16(0, 0); SBAR();
    LDBS(1, 0, 1);
    SBAR(); LGKM0(); MFMA16(0, 1); SBAR();
    LDA(0, 1);
    SBAR(); LGKM0(); MFMA16(1, 1); SBAR();
    VMCNT0();
    SBAR(); MFMA16(1, 0); SBAR();
    LDA(1, 0); LDBS(0, 1, 0);
    LGKM8();
    SBAR(); LGKM0(); MFMA16(0, 0); SBAR();
    LDBS(1, 1, 1);
    SBAR(); LGKM0(); MFMA16(0, 1); SBAR();
    LDA(1, 1);
    SBAR(); LGKM0(); MFMA16(1, 1); SBAR();
    MFMA16(1, 0);
  }
  GU_EPI(c + 16 * (ntiles - 1));
#undef PSTG_A
#undef PSTG_B
#undef LDA
#undef LDBS
#undef MFMA16
#undef GU_EPI
}

// ---------------- down GEMM (frag-once schedule, single tile) --------------
__global__ __launch_bounds__(512, 1) void gemm_down(
    const u16* __restrict__ A, const u16* __restrict__ Bl,
    const u16* __restrict__ Bv, const int* __restrict__ tt,
    float* __restrict__ O) {
  constexpr int KB = 22016;
  constexpr int NK = KB / 128;  // 172
  __shared__ u16 sA[2][2][128][64];
  __shared__ u16 sB[2][2][128][64];

  const int bid = blockIdx.x;
  const int wg = (bid & 7) * 32 + (bid >> 3);
  const int mT = wg & 15;
  const int nT = wg >> 4;

  const int t = threadIdx.x;
  const int lane = t & 63;
  const int rlo = lane & 15;
  const int hi = lane >> 4;
  const int wn = (t >> 6) & 3;
  const int wm = (t >> 8) & 1;

  const int side = tt[mT << 8];
  const u16* B = side ? Bl : Bv;

  const int rowq = t >> 3;
  const int gsw = ((t & 7) ^ (rowq & 7)) << 4;
  const char* srcA = (const char*)A + (size_t)(mT * 256 + rowq) * KB + gsw;
  const char* srcB = (const char*)B + (size_t)(nT * 256 + rowq) * KB + gsw;
  char* ldsA = (char*)&sA[0][0][0][0];
  char* ldsB = (char*)&sB[0][0][0][0];
  const int woff = (t & 448) << 4;

#define STG_A(d, h, kt)                                                        \
  do {                                                                         \
    GLOAD16(srcA + (size_t)((h) * 128) * KB + (kt) * 128,                      \
            ldsA + (d) * 32768 + (h) * 16384 + woff);                          \
    GLOAD16(srcA + (size_t)((h) * 128 + 64) * KB + (kt) * 128,                 \
            ldsA + (d) * 32768 + (h) * 16384 + 8192 + woff);                   \
  } while (0)
#define STG_B(d, h, kt)                                                        \
  do {                                                                         \
    GLOAD16(srcB + (size_t)((h) * 128) * KB + (kt) * 128,                      \
            ldsB + (d) * 32768 + (h) * 16384 + woff);                          \
    GLOAD16(srcB + (size_t)((h) * 128 + 64) * KB + (kt) * 128,                 \
            ldsB + (d) * 32768 + (h) * 16384 + 8192 + woff);                   \
  } while (0)

  const int cxa = (hi ^ (rlo & 7)) << 4;
  const int cxb = ((4 + hi) ^ (rlo & 7)) << 4;
  const int arow = (wm * 64 + rlo) * 128;
  const int brow = (wn * 32 + rlo) * 128;

  s16x8 af[4][2], bf[2][2][2];
  f32x4 acc[8][4];
  const f32x4 z = {0.f, 0.f, 0.f, 0.f};
#pragma unroll
  for (int i = 0; i < 8; ++i)
#pragma unroll
    for (int j = 0; j < 4; ++j) acc[i][j] = z;

#define LDA(d, mh)                                                             \
  do {                                                                         \
    _Pragma("unroll") for (int fi = 0; fi < 4; ++fi) {                         \
      const char* p = ldsA + (d) * 32768 + (mh) * 16384 + arow + fi * 2048;    \
      af[fi][0] = *(const s16x8*)(p + cxa);                                    \
      af[fi][1] = *(const s16x8*)(p + cxb);                                    \
    }                                                                          \
  } while (0)
#define LDBS(bi, d, nh)                                                        \
  do {                                                                         \
    _Pragma("unroll") for (int gi = 0; gi < 2; ++gi) {                         \
      const char* p = ldsB + (d) * 32768 + (nh) * 16384 + brow + gi * 2048;    \
      bf[bi][gi][0] = *(const s16x8*)(p + cxa);                                \
      bf[bi][gi][1] = *(const s16x8*)(p + cxb);                                \
    }                                                                          \
  } while (0)
#define MFMA16(mh, nh)                                                         \
  do {                                                                         \
    __builtin_amdgcn_s_setprio(1);                                             \
    _Pragma("unroll") for (int fi = 0; fi < 4; ++fi)                           \
        _Pragma("unroll") for (int gi = 0; gi < 2; ++gi) {                     \
      acc[(mh)*4 + fi][(nh)*2 + gi] = __builtin_amdgcn_mfma_f32_16x16x32_bf16( \
          af[fi][0], bf[nh][gi][0], acc[(mh)*4 + fi][(nh)*2 + gi], 0, 0, 0);   \
      acc[(mh)*4 + fi][(nh)*2 + gi] = __builtin_amdgcn_mfma_f32_16x16x32_bf16( \
          af[fi][1], bf[nh][gi][1], acc[(mh)*4 + fi][(nh)*2 + gi], 0, 0, 0);   \
    }                                                                          \
    __builtin_amdgcn_s_setprio(0);                                             \
  } while (0)

  STG_A(0, 0, 0); STG_B(0, 0, 0); STG_B(0, 1, 0); STG_A(0, 1, 0);
  STG_A(1, 0, 1); STG_B(1, 0, 1); STG_B(1, 1, 1);
  VMCNT4();
  SBAR();

  for (int T = 0; T < NK - 2; T += 2) {
    LDA(0, 0); LDBS(0, 0, 0);
    STG_A(1, 1, T + 1);
    LGKM8();
    SBAR(); LGKM0(); MFMA16(0, 0); SBAR();
    LDBS(1, 0, 1);
    STG_A(0, 0, T + 2);
    SBAR(); LGKM0(); MFMA16(0, 1); SBAR();
    LDA(0, 1);
    STG_B(0, 0, T + 2);
    SBAR(); LGKM0(); MFMA16(1, 1); SBAR();
    STG_B(0, 1, T + 2);
    VMCNT4();
    SBAR(); MFMA16(1, 0); SBAR();
    LDA(1, 0); LDBS(0, 1, 0);
    STG_A(0, 1, T + 2);
    LGKM8();
    SBAR(); LGKM0(); MFMA16(0, 0); SBAR();
    LDBS(1, 1, 1);
    STG_A(1, 0, T + 3);
    SBAR(); LGKM0(); MFMA16(0, 1); SBAR();
    LDA(1, 1);
    STG_B(1, 0, T + 3);
    SBAR(); LGKM0(); MFMA16(1, 1); SBAR();
    STG_B(1, 1, T + 3);
    VMCNT4();
    SBAR(); MFMA16(1, 0); SBAR();
  }
  {
    LDA(0, 0); LDBS(0, 0, 0);
    STG_A(1, 1, NK - 1);
    LGKM8();
    SBAR(); LGKM0(); MFMA16(0, 0); SBAR();
    LDBS(1, 0, 1);
    SBAR(); LGKM0(); MFMA16(0, 1); SBAR();
    LDA(0, 1);
    SBAR(); LGKM0(); MFMA16(1, 1); SBAR();
    VMCNT0();
    SBAR(); MFMA16(1, 0); SBAR();
    LDA(1, 0); LDBS(0, 1, 0);
    LGKM8();
    SBAR(); LGKM0(); MFMA16(0, 0); SBAR();
    LDBS(1, 1, 1);
    SBAR(); LGKM0(); MFMA16(0, 1); SBAR();
    LDA(1, 1);
    SBAR(); LGKM0(); MFMA16(1, 1); SBAR();
    MFMA16(1, 0);
  }

#pragma unroll
  for (int mh = 0; mh < 2; ++mh)
#pragma unroll
    for (int fi = 0; fi < 4; ++fi) {
      const int row0 = mT * 256 + mh * 128 + wm * 64 + fi * 16 + hi * 4;
#pragma unroll
      for (int nh = 0; nh < 2; ++nh)
#pragma unroll
        for (int gi = 0; gi < 2; ++gi) {
          const int col = nT * 256 + nh * 128 + wn * 32 + gi * 16 + rlo;
          const f32x4 a = acc[mh * 4 + fi][nh * 2 + gi];
#pragma unroll
          for (int r = 0; r < 4; ++r)
            O[(size_t)(row0 + r) * 4096 + col] = a[r];
        }
    }
#undef STG_A
#undef STG_B
#undef LDA
#undef LDBS
#undef MFMA16
}

extern "C" void kernel_launch(void* const* d_in, const int* in_sizes, int n_in,
                              void* d_out, int out_size, void* d_ws, size_t ws_size,
                              hipStream_t stream) {
  (void)in_sizes; (void)n_in; (void)out_size; (void)ws_size;
  const float* x  = (const float*)d_in[0];
  const int*   tt = (const int*)d_in[1];
  const float* lg = (const float*)d_in[2];
  const float* lu = (const float*)d_in[3];
  const float* ld = (const float*)d_in[4];
  const float* vg = (const float*)d_in[5];
  const float* vu = (const float*)d_in[6];
  const float* vd = (const float*)d_in[7];

  u16* ws  = (u16*)d_ws;
  u16* xbf = ws;                        // 4096*4096            = 16,777,216
  u16* GUl = xbf + 16777216;            // 22016*4096           = 90,177,536
  u16* GUv = GUl + 90177536;
  u16* ldT = GUv + 90177536;            // 4096*11008           = 45,088,768
  u16* vdT = ldT + 45088768;
  u16* hbuf = vdT + 45088768;           // 4096*11008
  // total: 332,398,592 u16 = ~665 MB

  prep_kernel<<<dim3(11008, 7), dim3(256), 0, stream>>>(
      lg, lu, vg, vu, ld, vd, x, GUl, GUv, ldT, vdT, xbf);
  gemm_gateup_persist<<<dim3(256), dim3(512), 0, stream>>>(
      xbf, GUl, GUv, tt, hbuf);
  gemm_down<<<dim3(256), dim3(512), 0, stream>>>(hbuf, ldT, vdT, tt, (float*)d_out);
}